// Round 5
// baseline (5417.028 us; speedup 1.0000x reference)
//
#include <hip/hip_runtime.h>

#define TT 1024
#define BB 64
#define DD 512
#define HH 512
#define NG 4       // batch groups (16 batches each)
#define BPG 16
#define NS 32      // hidden slices (16 units each)
#define UPS 16
#define NTHR 256

typedef short s8v __attribute__((ext_vector_type(8)));
typedef float f4v __attribute__((ext_vector_type(4)));
typedef int i4v __attribute__((ext_vector_type(4)));

static __device__ __forceinline__ unsigned short f2bf(float f) {
  union { float f; unsigned int u; } v; v.f = f;
  unsigned int r = v.u + 0x7FFFu + ((v.u >> 16) & 1u);  // RNE
  return (unsigned short)(r >> 16);
}

// Coherent (L3) accesses: sc0 sc1 bypass L1+L2 — no compiler wbl2/inv.
static __device__ __forceinline__ i4v ld_b128_cohere(const void* p) {
  i4v r;
  asm volatile("global_load_dwordx4 %0, %1, off sc0 sc1"
               : "=v"(r) : "v"(p) : "memory");
  return r;
}
static __device__ __forceinline__ int ld_b32_cohere(const void* p) {
  int r;
  asm volatile("global_load_dword %0, %1, off sc0 sc1\n\t"
               "s_waitcnt vmcnt(0)"
               : "=v"(r) : "v"(p) : "memory");
  return r;
}
static __device__ __forceinline__ void st_b32_cohere(void* p, unsigned int v) {
  asm volatile("global_store_dword %0, %1, off sc0 sc1"
               :: "v"(p), "v"(v) : "memory");
}
static __device__ __forceinline__ void st_b64_cohere(void* p,
                                                     unsigned long long v) {
  asm volatile("global_store_dwordx2 %0, %1, off sc0 sc1"
               :: "v"(p), "v"(v) : "memory");
}
static __device__ __forceinline__ unsigned int cvtpk_bf16(float lo, float hi) {
  unsigned int r;
  asm("v_cvt_pk_bf16_f32 %0, %1, %2" : "=v"(r) : "v"(lo), "v"(hi));
  return r;
}

// Reset hint flags each launch (graph replays rerun this -> hints effective
// on every timed replay, not just run 1).
__global__ void __launch_bounds__(256, 1) qlstm_init(int* flags) {
  st_b32_cohere(flags + threadIdx.x, 0u);
}

// x A-tile [16 rows][512 k] bf16, XOR-swizzled (row stride 1024B would be a
// 32-way conflict on ds_read_b128).
#define XSWZ(row, kbyte) ((((row) * 1024) + (kbyte)) ^ (((row) & 7) << 4))

__global__ void __launch_bounds__(NTHR, 1) qlstm_main(
    const float* __restrict__ X,
    const float* __restrict__ Wf, const float* __restrict__ bfp,
    const float* __restrict__ Wi, const float* __restrict__ bip,
    const float* __restrict__ Wg, const float* __restrict__ bgp,
    const float* __restrict__ Wo, const float* __restrict__ bop,
    const float* __restrict__ phase,
    float* __restrict__ out, int* __restrict__ flags,
    unsigned long long* __restrict__ hbuf64) {
  __shared__ char at[2][16384];          // x A-tile double buffer
  __shared__ float zbuf[2][2][2][64][4]; // zx [parity][uh][tile][lane][i]
  const int tid   = threadIdx.x;
  const int wv    = tid >> 6;
  const int lane  = tid & 63;
  const int n     = lane & 15;
  const int kg    = lane >> 4;
  const int group = blockIdx.x & (NG - 1);
  const int slice = blockIdx.x / NG;
  const int b0 = group * BPG;
  const int u0 = slice * UPS;
  const bool isH = (wv >= 2);
  const int uh = wv & 1;   // unit half (8 units each)

  // Per-wave persistent weights (MFMA B-frags), 2 packed tiles:
  //  tile0: n<8 -> (f, unit n), n>=8 -> (i, unit n-8); tile1: (g,o).
  //  Service waves (0,1): K rows 0..511 (x-part); h-waves (2,3): 512..1023.
  const float* Wt0 = (n < 8) ? Wf : Wi;
  const float* Wt1 = (n < 8) ? Wg : Wo;
  const int wcol  = u0 + uh * 8 + (n & 7);
  const int krow0 = (isH ? 512 : 0) + kg * 8;
  s8v wreg0[16], wreg1[16];
#pragma unroll
  for (int kc = 0; kc < 16; ++kc) {
#pragma unroll
    for (int j = 0; j < 8; ++j) {
      const int row = krow0 + kc * 32 + j;
      wreg0[kc][j] = (short)f2bf(Wt0[(size_t)row * HH + wcol]);
      wreg1[kc][j] = (short)f2bf(Wt1[(size_t)row * HH + wcol]);
    }
  }

  if (!isH) {
    // ============ service waves: x-GEMM producer (full-step slack) ==========
    const int st  = uh * 64 + lane;
    const int row = st >> 3, seg = st & 7;
    // stage X[t2] -> at[t2&1]: 16 float4 issued as one burst (latency-tolerant)
#define STAGE_X(t2)                                                            \
  {                                                                            \
    const float4* Xr =                                                         \
        (const float4*)(X + ((size_t)(t2)*BB + b0 + row) * DD + seg * 64);     \
    float4 xv[16];                                                             \
    _Pragma("unroll") for (int j = 0; j < 16; ++j) xv[j] = Xr[j];              \
    _Pragma("unroll") for (int i = 0; i < 8; ++i) {                            \
      i4v w;                                                                   \
      w[0] = cvtpk_bf16(xv[2 * i].x, xv[2 * i].y);                             \
      w[1] = cvtpk_bf16(xv[2 * i].z, xv[2 * i].w);                             \
      w[2] = cvtpk_bf16(xv[2 * i + 1].x, xv[2 * i + 1].y);                     \
      w[3] = cvtpk_bf16(xv[2 * i + 1].z, xv[2 * i + 1].w);                     \
      *(i4v*)(at[(t2)&1] + XSWZ(row, seg * 128 + i * 16)) = w;                 \
    }                                                                          \
  }
#define X_MFMA(tp)                                                             \
  {                                                                            \
    f4v a0 = {0.f, 0.f, 0.f, 0.f}, a1 = {0.f, 0.f, 0.f, 0.f};                  \
    _Pragma("unroll") for (int kc = 0; kc < 16; ++kc) {                        \
      const s8v af = *(const s8v*)(at[tp] + XSWZ(n, kg * 16 + kc * 64));       \
      a0 = __builtin_amdgcn_mfma_f32_16x16x32_bf16(af, wreg0[kc], a0, 0, 0, 0);\
      a1 = __builtin_amdgcn_mfma_f32_16x16x32_bf16(af, wreg1[kc], a1, 0, 0, 0);\
    }                                                                          \
    *(f4v*)&zbuf[tp][uh][0][lane][0] = a0;                                     \
    *(f4v*)&zbuf[tp][uh][1][lane][0] = a1;                                     \
  }
    STAGE_X(0);
    __syncthreads();                      // P1
    X_MFMA(0);                            // zx(0) -> zbuf[0]
    STAGE_X(1);
    __syncthreads();                      // P2
    for (int t = 0; t < TT; ++t) {
      if (t + 1 < TT) X_MFMA((t + 1) & 1);   // zx(t+1) from tile staged last step
      if (t + 2 < TT) STAGE_X(t + 2);        // X(t+2) -> at[t&1]
      __syncthreads();
    }
  } else {
    // ================= h-waves: the critical path =================
    const int uu = u0 + uh * 8 + (n & 7);
    const float bz0 = bfp[uu] + phase[uu];
    const float bz1 = bip[uu] + phase[uu];
    const float bz2 = bgp[uu] + phase[uu];
    const float bz3 = bop[uu] + phase[uu];
    float cst[4] = {0.f, 0.f, 0.f, 0.f};
    int* myflag = flags + (uh * NG + group) * NS + slice;
    const int* pollp = flags + ((lane >> 5) * NG + group) * NS + (lane & 31);

    __syncthreads();  // P1
    __syncthreads();  // P2
    for (int t = 0; t < TT; ++t) {
      f4v px0 = *(const f4v*)&zbuf[t & 1][uh][0][lane][0];
      f4v px1 = *(const f4v*)&zbuf[t & 1][uh][1][lane][0];
      f4v a0 = {0.f, 0.f, 0.f, 0.f}, a1 = {0.f, 0.f, 0.f, 0.f};
      if (t > 0) {
        const int tm1 = t - 1;
        // hint poll (cheap, 4B/lane). Unsigned cmp: 0xAA poison passes ->
        // verify loop below is the correctness backstop.
        for (;;) {
          const unsigned v = (unsigned)ld_b32_cohere(pollp);
          if (__all(v >= (unsigned)t)) break;
          __builtin_amdgcn_s_sleep(1);
        }
        // tagged h load + verify: {bf16-pair, tag} u64 words; all 64 tags
        // must equal t-1. No producer-side ordering needed.
        const unsigned long long* hb = hbuf64 + (size_t)(tm1 & 1) * BB * 256 +
                                       (size_t)(b0 + n) * 256 + kg * 4;
        i4v hf[32];
        for (;;) {
#pragma unroll
          for (int kc = 0; kc < 16; ++kc) {
            hf[2 * kc]     = ld_b128_cohere(hb + kc * 16);
            hf[2 * kc + 1] = ld_b128_cohere(hb + kc * 16 + 2);
          }
          asm volatile("s_waitcnt vmcnt(0)" ::: "memory");
          __builtin_amdgcn_sched_barrier(0);
          int bad = 0;
#pragma unroll
          for (int j = 0; j < 32; ++j)
            bad |= (hf[j][1] ^ tm1) | (hf[j][3] ^ tm1);
          if (__all(bad == 0)) break;
          __builtin_amdgcn_s_sleep(1);
        }
#pragma unroll
        for (int kc = 0; kc < 16; ++kc) {
          union { i4v i; s8v s; } af;
          af.i[0] = hf[2 * kc][0];
          af.i[1] = hf[2 * kc][2];
          af.i[2] = hf[2 * kc + 1][0];
          af.i[3] = hf[2 * kc + 1][2];
          a0 = __builtin_amdgcn_mfma_f32_16x16x32_bf16(af.s, wreg0[kc], a0, 0, 0, 0);
          a1 = __builtin_amdgcn_mfma_f32_16x16x32_bf16(af.s, wreg1[kc], a1, 0, 0, 0);
        }
      }
      // gates in-register: lane pair (n, n^8) holds {f,i} / {g,o}
      float hv[4];
#pragma unroll
      for (int i = 0; i < 4; ++i) {
        const float s0 = a0[i] + px0[i];
        const float s1 = a1[i] + px1[i];
        const float p0 = __shfl_xor(s0, 8);
        const float p1 = __shfl_xor(s1, 8);
        const bool lo = (n < 8);
        const float zf = (lo ? s0 : p0) + bz0;
        const float zi = (lo ? p0 : s0) + bz1;
        const float zg = (lo ? s1 : p1) + bz2;
        const float zo = (lo ? p1 : s1) + bz3;
        const float fg = 1.f / (1.f + __expf(-zf));
        const float ig = 1.f / (1.f + __expf(-zi));
        const float gg = 1.f - 2.f / (__expf(2.f * zg) + 1.f);
        const float og = 1.f / (1.f + __expf(-zo));
        cst[i] = fg * cst[i] + ig * gg;
        hv[i] = og * (1.f - 2.f / (__expf(2.f * cst[i]) + 1.f));
      }
      // publish tagged h (no drain!) + hint flag (unordered hint)
      float hn[4];
#pragma unroll
      for (int i = 0; i < 4; ++i) hn[i] = __shfl_down(hv[i], 1);
      if (n < 8 && !(n & 1)) {
#pragma unroll
        for (int i = 0; i < 4; ++i) {
          const unsigned long long d =
              ((unsigned long long)(unsigned)t << 32) |
              (unsigned long long)cvtpk_bf16(hv[i], hn[i]);
          st_b64_cohere(hbuf64 + (size_t)(t & 1) * BB * 256 +
                            (size_t)(b0 + 4 * kg + i) * 256 +
                            (u0 + uh * 8 + n) / 2,
                        d);
        }
      }
      if (lane == 0) st_b32_cohere(myflag, (unsigned int)(t + 1));
      if (n < 8) {
#pragma unroll
        for (int i = 0; i < 4; ++i)
          out[(size_t)t * BB * HH + (size_t)(b0 + 4 * kg + i) * HH + uu] = hv[i];
        if (t == TT - 1) {
#pragma unroll
          for (int i = 0; i < 4; ++i) {
            out[(size_t)TT * BB * HH + (size_t)(b0 + 4 * kg + i) * HH + uu] = hv[i];
            out[(size_t)TT * BB * HH + BB * HH +
                (size_t)(b0 + 4 * kg + i) * HH + uu] = cst[i];
          }
        }
      }
      __syncthreads();
    }
  }
}

extern "C" void kernel_launch(void* const* d_in, const int* in_sizes, int n_in,
                              void* d_out, int out_size, void* d_ws,
                              size_t ws_size, hipStream_t stream) {
  const float* X   = (const float*)d_in[0];
  const float* Wf  = (const float*)d_in[1];
  const float* bfp = (const float*)d_in[2];
  const float* Wi  = (const float*)d_in[3];
  const float* bip = (const float*)d_in[4];
  const float* Wg  = (const float*)d_in[5];
  const float* bgp = (const float*)d_in[6];
  const float* Wo  = (const float*)d_in[7];
  const float* bop = (const float*)d_in[8];
  const float* ph  = (const float*)d_in[9];
  float* out = (float*)d_out;

  // ws: [0, 256KB) tagged-h double buffer {bf16 pair | u32 tag} u64 words
  //     [256KB, +1KB) hint flags[2][NG][NS]
  unsigned long long* hbuf64 = (unsigned long long*)d_ws;
  int* flags = (int*)((char*)d_ws + 262144);

  qlstm_init<<<1, 256, 0, stream>>>(flags);
  qlstm_main<<<NG * NS, NTHR, 0, stream>>>(X, Wf, bfp, Wi, bip, Wg, bgp, Wo,
                                           bop, ph, out, flags, hbuf64);
}